// Round 1
// baseline (86.465 us; speedup 1.0000x reference)
//
#include <hip/hip_runtime.h>

// SSKernelNPLR: Cauchy kernel + rank-1 Woodbury + irfft(L=2048), H=256, N=64.
// One block per h. Stage A: k_f[0..1024] (stabilized form, no huge z).
// Stage B: pack Hermitian half-spectrum into M=1024 complex sequence.
// Stage C: Stockham radix-2 inverse FFT (autosort, 10 stages, LDS ping-pong).
// Stage D: x[2m]=Re z[m]/M, x[2m+1]=Im z[m]/M.

#define HH 256
#define NN 64
#define LL 2048
#define MM 1024   // LL/2
#define NT 512    // threads per block (8 waves)

#define PI_OVER_1024 0.0030679615757712823f  // 2*pi/2048, stage A/B angle unit
#define PI_OVER_512  0.0061359231515425647f  // 2*pi/1024, FFT twiddle unit

__global__ __launch_bounds__(NT) void ssk_fused(
    const float* __restrict__ Cin, const float* __restrict__ Bin,
    const float* __restrict__ Pin, const float* __restrict__ Win,
    const float* __restrict__ logdt, float* __restrict__ out)
{
    __shared__ float2 sW[NN];     // w * dt
    __shared__ float2 sV00[NN], sV01[NN], sV10[NN], sV11[NN];
    __shared__ float2 sX[MM + 1]; // k_f, f = 0..1024
    __shared__ float2 sA[MM];     // FFT ping
    __shared__ float2 sBf[MM];    // FFT pong

    const int h = blockIdx.x;
    const int t = threadIdx.x;
    const float dtv = expf(logdt[h]);

    // ---- stage 0: stage per-n products in LDS ----
    if (t < NN) {
        const int base = (h * NN + t) * 2;
        const float Br = Bin[base], Bi = Bin[base + 1];
        const float Cr = Cin[base], Ci = Cin[base + 1];
        const float Pr = Pin[base], Pi = Pin[base + 1];
        sW[t]   = make_float2(Win[base] * dtv, Win[base + 1] * dtv);
        // v00 = B*C, v01 = B*conj(P), v10 = P*C, v11 = P*conj(P) (real)
        sV00[t] = make_float2(Br * Cr - Bi * Ci, Br * Ci + Bi * Cr);
        sV01[t] = make_float2(Br * Pr + Bi * Pi, Bi * Pr - Br * Pi);
        sV10[t] = make_float2(Pr * Cr - Pi * Ci, Pr * Ci + Pi * Cr);
        sV11[t] = make_float2(Pr * Pr + Pi * Pi, 0.0f);
    }
    __syncthreads();

    // ---- stage A: Cauchy + Woodbury -> sX[f] ----
    // omega = exp(-2*pi*i*f/L) = (co, -si); u = 1+omega
    // den_n = 2(1-omega) - w_dt[n]*u ;  1/(z - w_dt) = u/den
    // s_ab  = sum_n v_ab/den
    // k_f   = 2*dt*( s00 - dt*u*s01*s10 / (1 + dt*u*s11) )   [2/(1+omega) folded in]
    for (int f = t; f <= MM; f += NT) {
        const float ang = PI_OVER_1024 * (float)f;
        float si, co;
        sincosf(ang, &si, &co);
        const float ur = 1.0f + co, ui = -si;
        const float t1r = 2.0f * (1.0f - co), t1i = 2.0f * si;

        float s00r = 0.f, s00i = 0.f, s01r = 0.f, s01i = 0.f;
        float s10r = 0.f, s10i = 0.f, s11r = 0.f, s11i = 0.f;
        #pragma unroll 4
        for (int n = 0; n < NN; ++n) {
            const float2 wd = sW[n];
            const float dr = t1r - (wd.x * ur - wd.y * ui);
            const float di = t1i - (wd.x * ui + wd.y * ur);
            const float inv = __builtin_amdgcn_rcpf(dr * dr + di * di);
            const float er = dr * inv, ei = -di * inv;
            float2 v;
            v = sV00[n]; s00r += v.x * er - v.y * ei; s00i += v.x * ei + v.y * er;
            v = sV01[n]; s01r += v.x * er - v.y * ei; s01i += v.x * ei + v.y * er;
            v = sV10[n]; s10r += v.x * er - v.y * ei; s10i += v.x * ei + v.y * er;
            v = sV11[n]; s11r += v.x * er;            s11i += v.x * ei;  // v11 imag == 0
        }
        const float gr = dtv * ur, gi = dtv * ui;              // g = dt*u
        const float numr = s01r * s10r - s01i * s10i;          // s01*s10
        const float numi = s01r * s10i + s01i * s10r;
        const float qr = 1.0f + (gr * s11r - gi * s11i);       // 1 + g*s11
        const float qi = gr * s11i + gi * s11r;
        const float tr = gr * numr - gi * numi;                // g*num
        const float ti = gr * numi + gi * numr;
        const float qinv = __builtin_amdgcn_rcpf(qr * qr + qi * qi);
        const float cr = (tr * qr + ti * qi) * qinv;           // (g*num)/(1+g*s11)
        const float ci = (ti * qr - tr * qi) * qinv;
        const float kr = 2.0f * dtv * (s00r - cr);
        float       ki = 2.0f * dtv * (s00i - ci);
        if (f == 0 || f == MM) ki = 0.0f;  // pocketfft c2r ignores Im at DC/Nyquist
        sX[f] = make_float2(kr, ki);
    }
    __syncthreads();

    // ---- stage B: Hermitian half-spectrum -> length-M complex sequence ----
    // E = (X[f] + conj(X[M-f]))/2 ; O = e^{+2*pi*i*f/L} * (X[f] - conj(X[M-f]))/2
    // Z = E + i*O
    for (int f = t; f < MM; f += NT) {
        const float2 a1 = sX[f];
        const float2 x2 = sX[MM - f];
        const float a2r = x2.x, a2i = -x2.y;
        const float er = 0.5f * (a1.x + a2r), eim = 0.5f * (a1.y + a2i);
        const float gr = 0.5f * (a1.x - a2r), gim = 0.5f * (a1.y - a2i);
        const float ang = PI_OVER_1024 * (float)f;
        float st, ct;
        sincosf(ang, &st, &ct);
        const float Or = ct * gr - st * gim;
        const float Oi = ct * gim + st * gr;
        sA[f] = make_float2(er - Oi, eim + Or);
    }
    __syncthreads();

    // ---- stage C: Stockham radix-2 inverse FFT (sign +), natural order out ----
    float2* cur = sA;
    float2* nxt = sBf;
    #pragma unroll
    for (int i = 0; i < 10; ++i) {
        const int s = 1 << i;
        const int b = t;           // NT == 512 == butterflies per stage
        if (b < 512) {
            const int j = b & ~(s - 1);             // s * p
            const float2 a = cur[b];
            const float2 c = cur[b + 512];
            const float sr = a.x + c.x, sim = a.y + c.y;
            const float dr = a.x - c.x, dim = a.y - c.y;
            const float ang = PI_OVER_512 * (float)j; // 2*pi*p/n == 2*pi*j/1024
            float st, ct;
            sincosf(ang, &st, &ct);
            nxt[b + j]     = make_float2(sr, sim);
            nxt[b + j + s] = make_float2(ct * dr - st * dim, ct * dim + st * dr);
        }
        __syncthreads();
        float2* tmp = cur; cur = nxt; nxt = tmp;
    }
    // 10 swaps -> result back in sA (== cur)

    // ---- stage D: de-interleave, scale by 1/M, coalesced float2 stores ----
    const float scale = 1.0f / (float)MM;
    float2* outv = (float2*)(out + (size_t)h * LL);
    for (int m = t; m < MM; m += NT) {
        const float2 z = cur[m];
        outv[m] = make_float2(z.x * scale, z.y * scale);
    }
}

extern "C" void kernel_launch(void* const* d_in, const int* in_sizes, int n_in,
                              void* d_out, int out_size, void* d_ws, size_t ws_size,
                              hipStream_t stream) {
    const float* C  = (const float*)d_in[0];
    const float* B  = (const float*)d_in[1];
    const float* P  = (const float*)d_in[2];
    const float* W  = (const float*)d_in[3];
    const float* ld = (const float*)d_in[4];
    // d_in[5] is L == 2048, compiled in as LL.
    float* out = (float*)d_out;
    ssk_fused<<<HH, NT, 0, stream>>>(C, B, P, W, ld, out);
}

// Round 2
// 77.030 us; speedup vs baseline: 1.1225x; 1.1225x over previous
//
#include <hip/hip_runtime.h>

// SSKernelNPLR: Cauchy + rank-1 Woodbury + irfft(L=2048), H=256, N=64.
// One block per h (grid 256 == CU count), 512 threads (8 waves).
// R2 changes vs R1: packed <2 x float> math in the Cauchy loop (v_pk_fma_f32),
// f=1024 handled analytically (u=0 -> k=dt*sum(v00r)/2) so stage A is exactly
// 2 uniform passes, __sincosf everywhere, per-n LDS data packed into
// 2x b128 + 1x b32 broadcast reads, IFFT 1/M scale folded into stage B.

typedef float v2f __attribute__((ext_vector_type(2)));

#define HH 256
#define NN 64
#define LL 2048
#define MM 1024   // LL/2
#define NT 512    // threads per block (8 waves)

#define PI_OVER_1024 0.0030679615757712823f  // 2*pi/2048
#define PI_OVER_512  0.0061359231515425647f  // 2*pi/1024

__global__ __launch_bounds__(NT) void ssk_fused(
    const float* __restrict__ Cin, const float* __restrict__ Bin,
    const float* __restrict__ Pin, const float* __restrict__ Win,
    const float* __restrict__ logdt, float* __restrict__ out)
{
    // per-n staging: [n*3+0]={wd.x,wd.y,v00.x,v00.y} [n*3+1]={v01.x,v01.y,v10.x,v10.y}
    //                [n*3+2]={v11r, -, -, -}
    __shared__ float4 sD4[NN * 3];
    __shared__ float2 sX[MM + 1]; // k_f, f = 0..1024
    __shared__ float2 sA[MM];     // FFT ping
    __shared__ float2 sBf[MM];    // FFT pong

    const int h = blockIdx.x;
    const int t = threadIdx.x;
    const float dtv = __expf(logdt[h]);

    // ---- stage 0: per-n products into LDS + analytic f=1024 term ----
    if (t < NN) {   // t<64 == wave 0 exactly
        const int base = (h * NN + t) * 2;
        const float Br = Bin[base], Bi = Bin[base + 1];
        const float Cr = Cin[base], Ci = Cin[base + 1];
        const float Pr = Pin[base], Pi = Pin[base + 1];
        const float v00r = Br * Cr - Bi * Ci, v00i = Br * Ci + Bi * Cr;
        sD4[t * 3 + 0] = make_float4(Win[base] * dtv, Win[base + 1] * dtv, v00r, v00i);
        sD4[t * 3 + 1] = make_float4(Br * Pr + Bi * Pi, Bi * Pr - Br * Pi,
                                     Pr * Cr - Pi * Ci, Pr * Ci + Pi * Cr);
        sD4[t * 3 + 2] = make_float4(Pr * Pr + Pi * Pi, 0.f, 0.f, 0.f);
        // f = L/2: omega=-1 -> u=0, den=4, Woodbury term vanishes:
        // k_f[1024] = 2*dt*sum_n(v00)/4 = dt*sum(v00r)/2  (imag forced 0)
        float r = v00r;
        #pragma unroll
        for (int off = 32; off; off >>= 1) r += __shfl_xor(r, off, 64);
        if (t == 0) sX[MM] = make_float2(0.5f * dtv * r, 0.f);
    }
    __syncthreads();

    // ---- stage A: Cauchy + Woodbury -> sX[f], f = t and t+512 ----
    // u = 1+omega; den_n = 2(1-omega) - w_dt[n]*u ; 1/(z-w_dt) = u/den
    // k_f = 2*dt*( s00 - dt*u*s01*s10 / (1 + dt*u*s11) )   [2/(1+omega) folded]
    const float* sDf = (const float*)sD4;
    #pragma unroll
    for (int rep = 0; rep < 2; ++rep) {
        const int f = t + rep * 512;
        float si, co;
        __sincosf(PI_OVER_1024 * (float)f, &si, &co);
        const v2f u  = {1.0f + co, -si};
        const v2f t1 = {2.0f * (1.0f - co), 2.0f * si};

        v2f s00 = {0.f, 0.f}, s01 = {0.f, 0.f}, s10 = {0.f, 0.f}, s11 = {0.f, 0.f};
        #pragma unroll 8
        for (int n = 0; n < NN; ++n) {
            const float4 q0 = sD4[n * 3 + 0];
            const float4 q1 = sD4[n * 3 + 1];
            const float v11 = sDf[n * 12 + 8];
            // den = t1 - wd*u   (wd = {q0.x,q0.y})
            v2f den = t1;
            den = den - (v2f){q0.x, q0.x} * u;
            den = den + (v2f){q0.y, q0.y} * (v2f){u.y, -u.x};
            const float inv = __builtin_amdgcn_rcpf(den.x * den.x + den.y * den.y);
            const v2f e  = den * (v2f){inv, -inv};   // e = 1/den = conj(den)/|den|^2
            const v2f es = {e.y, e.x};
            s00 = s00 + (v2f){q0.z, q0.z} * e;
            s00 = s00 + (v2f){-q0.w, q0.w} * es;
            s01 = s01 + (v2f){q1.x, q1.x} * e;
            s01 = s01 + (v2f){-q1.y, q1.y} * es;
            s10 = s10 + (v2f){q1.z, q1.z} * e;
            s10 = s10 + (v2f){-q1.w, q1.w} * es;
            s11 = s11 + (v2f){v11, v11} * e;         // v11 imag == 0
        }
        const float gr = dtv * u.x, gi = dtv * u.y;          // g = dt*u
        const float numr = s01.x * s10.x - s01.y * s10.y;    // s01*s10
        const float numi = s01.x * s10.y + s01.y * s10.x;
        const float qr = 1.0f + (gr * s11.x - gi * s11.y);   // 1 + g*s11
        const float qi = gr * s11.y + gi * s11.x;
        const float tr = gr * numr - gi * numi;              // g*num
        const float ti = gr * numi + gi * numr;
        const float qinv = __builtin_amdgcn_rcpf(qr * qr + qi * qi);
        const float cr = (tr * qr + ti * qi) * qinv;
        const float ci = (ti * qr - tr * qi) * qinv;
        const float kr = 2.0f * dtv * (s00.x - cr);
        float       ki = 2.0f * dtv * (s00.y - ci);
        if (f == 0) ki = 0.0f;   // pocketfft c2r ignores Im at DC
        sX[f] = make_float2(kr, ki);
    }
    __syncthreads();

    // ---- stage B: Hermitian half-spectrum -> length-M complex seq (scale folded) ----
    const float HS = 4.8828125e-4f;  // 0.5 / 1024  (pack half + IFFT 1/M)
    for (int f = t; f < MM; f += NT) {
        const float2 a1 = sX[f];
        const float2 x2 = sX[MM - f];
        const float er  = HS * (a1.x + x2.x), eim = HS * (a1.y - x2.y);
        const float gr  = HS * (a1.x - x2.x), gim = HS * (a1.y + x2.y);
        float st, ct;
        __sincosf(PI_OVER_1024 * (float)f, &st, &ct);
        const float Or = ct * gr - st * gim;
        const float Oi = ct * gim + st * gr;
        sA[f] = make_float2(er - Oi, eim + Or);
    }
    __syncthreads();

    // ---- stage C: Stockham radix-2 inverse FFT (sign +), natural order out ----
    float2* cur = sA;
    float2* nxt = sBf;
    #pragma unroll
    for (int i = 0; i < 10; ++i) {
        const int s = 1 << i;
        const int b = t;                      // NT == 512 butterflies/stage
        const int j = b & ~(s - 1);           // s * p
        const float2 a = cur[b];
        const float2 c = cur[b + 512];
        const float sr = a.x + c.x, sim = a.y + c.y;
        const float dr = a.x - c.x, dim = a.y - c.y;
        float st, ct;
        __sincosf(PI_OVER_512 * (float)j, &st, &ct);
        nxt[b + j]     = make_float2(sr, sim);
        nxt[b + j + s] = make_float2(ct * dr - st * dim, ct * dim + st * dr);
        __syncthreads();
        float2* tmp = cur; cur = nxt; nxt = tmp;
    }
    // 10 swaps -> result back in sA (== cur)

    // ---- stage D: x[2m]=Re, x[2m+1]=Im (scale already folded), coalesced ----
    float2* outv = (float2*)(out + (size_t)h * LL);
    for (int m = t; m < MM; m += NT) outv[m] = cur[m];
}

extern "C" void kernel_launch(void* const* d_in, const int* in_sizes, int n_in,
                              void* d_out, int out_size, void* d_ws, size_t ws_size,
                              hipStream_t stream) {
    const float* C  = (const float*)d_in[0];
    const float* B  = (const float*)d_in[1];
    const float* P  = (const float*)d_in[2];
    const float* W  = (const float*)d_in[3];
    const float* ld = (const float*)d_in[4];
    // d_in[5] is L == 2048, compiled in as LL.
    float* out = (float*)d_out;
    ssk_fused<<<HH, NT, 0, stream>>>(C, B, P, W, ld, out);
}

// Round 3
// 75.236 us; speedup vs baseline: 1.1493x; 1.0238x over previous
//
#include <hip/hip_runtime.h>

// SSKernelNPLR: Cauchy + rank-1 Woodbury + irfft(L=2048), H=256, N=64.
// R3: 256 threads/block (4 waves), grid 256 (1 block/CU). Stage A gives each
// thread FOUR f values so the per-n LDS broadcast (2x b128 + b32) is read once
// per wave and amortized over 4 accumulator sets -> ~4x less LDS-pipe traffic
// than R2 (8 waves x 2 passes). 1 wave/SIMD, so VGPR pressure is free; unroll 4.
// FFT: Stockham radix-2, 2 butterflies/thread, 10 stages.

typedef float v2f __attribute__((ext_vector_type(2)));

#define HH 256
#define NN 64
#define LL 2048
#define MM 1024   // LL/2
#define NT 256    // threads per block (4 waves)
#define FPT 4     // f values per thread in stage A

#define PI_OVER_1024 0.0030679615757712823f  // 2*pi/2048
#define PI_OVER_512  0.0061359231515425647f  // 2*pi/1024

__global__ __launch_bounds__(NT) void ssk_fused(
    const float* __restrict__ Cin, const float* __restrict__ Bin,
    const float* __restrict__ Pin, const float* __restrict__ Win,
    const float* __restrict__ logdt, float* __restrict__ out)
{
    // per-n staging: [n*3+0]={wd.x,wd.y,v00.x,v00.y} [n*3+1]={v01.x,v01.y,v10.x,v10.y}
    //                [n*3+2]={v11r, -, -, -}
    __shared__ float4 sD4[NN * 3];
    __shared__ float2 sX[MM + 1]; // k_f, f = 0..1024
    __shared__ float2 sA[MM];     // FFT ping
    __shared__ float2 sBf[MM];    // FFT pong

    const int h = blockIdx.x;
    const int t = threadIdx.x;
    const float dtv = __expf(logdt[h]);

    // ---- stage 0: per-n products into LDS + analytic f=1024 term ----
    if (t < NN) {   // t<64 == wave 0 exactly
        const int base = (h * NN + t) * 2;
        const float Br = Bin[base], Bi = Bin[base + 1];
        const float Cr = Cin[base], Ci = Cin[base + 1];
        const float Pr = Pin[base], Pi = Pin[base + 1];
        const float v00r = Br * Cr - Bi * Ci, v00i = Br * Ci + Bi * Cr;
        sD4[t * 3 + 0] = make_float4(Win[base] * dtv, Win[base + 1] * dtv, v00r, v00i);
        sD4[t * 3 + 1] = make_float4(Br * Pr + Bi * Pi, Bi * Pr - Br * Pi,
                                     Pr * Cr - Pi * Ci, Pr * Ci + Pi * Cr);
        sD4[t * 3 + 2] = make_float4(Pr * Pr + Pi * Pi, 0.f, 0.f, 0.f);
        // f = L/2: omega=-1 -> u=0, den=4, Woodbury term vanishes:
        // k_f[1024] = 2*dt*sum_n(v00)/4 = dt*sum(v00r)/2  (imag forced 0)
        float r = v00r;
        #pragma unroll
        for (int off = 32; off; off >>= 1) r += __shfl_xor(r, off, 64);
        if (t == 0) sX[MM] = make_float2(0.5f * dtv * r, 0.f);
    }
    __syncthreads();

    // ---- stage A: Cauchy + Woodbury -> sX[f], f = t + rep*256, rep=0..3 ----
    // u = 1+omega; den_n = 2(1-omega) - w_dt[n]*u ; 1/(z-w_dt) = u/den
    // k_f = 2*dt*( s00 - dt*u*s01*s10 / (1 + dt*u*s11) )   [2/(1+omega) folded]
    {
        const float* sDf = (const float*)sD4;
        v2f u[FPT], t1[FPT];
        v2f s00[FPT], s01[FPT], s10[FPT], s11[FPT];
        #pragma unroll
        for (int rep = 0; rep < FPT; ++rep) {
            const int f = t + rep * NT;
            float si, co;
            __sincosf(PI_OVER_1024 * (float)f, &si, &co);
            u[rep]  = (v2f){1.0f + co, -si};
            t1[rep] = (v2f){2.0f * (1.0f - co), 2.0f * si};
            s00[rep] = (v2f){0.f, 0.f}; s01[rep] = (v2f){0.f, 0.f};
            s10[rep] = (v2f){0.f, 0.f}; s11[rep] = (v2f){0.f, 0.f};
        }
        #pragma unroll 4
        for (int n = 0; n < NN; ++n) {
            const float4 q0 = sD4[n * 3 + 0];   // wd.x wd.y v00r v00i
            const float4 q1 = sD4[n * 3 + 1];   // v01r v01i v10r v10i
            const float v11 = sDf[n * 12 + 8];
            #pragma unroll
            for (int rep = 0; rep < FPT; ++rep) {
                v2f den = t1[rep];
                den = den - (v2f){q0.x, q0.x} * u[rep];
                den = den + (v2f){q0.y, q0.y} * (v2f){u[rep].y, -u[rep].x};
                const float inv = __builtin_amdgcn_rcpf(den.x * den.x + den.y * den.y);
                const v2f e  = den * (v2f){inv, -inv};  // 1/den = conj(den)/|den|^2
                const v2f es = {e.y, e.x};
                s00[rep] = s00[rep] + (v2f){q0.z, q0.z} * e;
                s00[rep] = s00[rep] + (v2f){-q0.w, q0.w} * es;
                s01[rep] = s01[rep] + (v2f){q1.x, q1.x} * e;
                s01[rep] = s01[rep] + (v2f){-q1.y, q1.y} * es;
                s10[rep] = s10[rep] + (v2f){q1.z, q1.z} * e;
                s10[rep] = s10[rep] + (v2f){-q1.w, q1.w} * es;
                s11[rep] = s11[rep] + (v2f){v11, v11} * e;   // v11 imag == 0
            }
        }
        #pragma unroll
        for (int rep = 0; rep < FPT; ++rep) {
            const int f = t + rep * NT;
            const float gr = dtv * u[rep].x, gi = dtv * u[rep].y;      // g = dt*u
            const float numr = s01[rep].x * s10[rep].x - s01[rep].y * s10[rep].y;
            const float numi = s01[rep].x * s10[rep].y + s01[rep].y * s10[rep].x;
            const float qr = 1.0f + (gr * s11[rep].x - gi * s11[rep].y); // 1+g*s11
            const float qi = gr * s11[rep].y + gi * s11[rep].x;
            const float tr = gr * numr - gi * numi;                      // g*num
            const float ti = gr * numi + gi * numr;
            const float qinv = __builtin_amdgcn_rcpf(qr * qr + qi * qi);
            const float cr = (tr * qr + ti * qi) * qinv;
            const float ci = (ti * qr - tr * qi) * qinv;
            const float kr = 2.0f * dtv * (s00[rep].x - cr);
            float       ki = 2.0f * dtv * (s00[rep].y - ci);
            if (f == 0) ki = 0.0f;   // pocketfft c2r ignores Im at DC
            sX[f] = make_float2(kr, ki);
        }
    }
    __syncthreads();

    // ---- stage B: Hermitian half-spectrum -> length-M complex seq (scale folded) ----
    const float HS = 4.8828125e-4f;  // 0.5 / 1024  (pack half + IFFT 1/M)
    #pragma unroll
    for (int rep = 0; rep < FPT; ++rep) {
        const int f = t + rep * NT;
        const float2 a1 = sX[f];
        const float2 x2 = sX[MM - f];
        const float er  = HS * (a1.x + x2.x), eim = HS * (a1.y - x2.y);
        const float gr  = HS * (a1.x - x2.x), gim = HS * (a1.y + x2.y);
        float st, ct;
        __sincosf(PI_OVER_1024 * (float)f, &st, &ct);
        const float Or = ct * gr - st * gim;
        const float Oi = ct * gim + st * gr;
        sA[f] = make_float2(er - Oi, eim + Or);
    }
    __syncthreads();

    // ---- stage C: Stockham radix-2 inverse FFT (sign +), 2 butterflies/thread ----
    float2* cur = sA;
    float2* nxt = sBf;
    #pragma unroll
    for (int i = 0; i < 10; ++i) {
        const int s = 1 << i;
        #pragma unroll
        for (int half = 0; half < 2; ++half) {
            const int b = t + half * NT;          // butterfly index in [0,512)
            const int j = b & ~(s - 1);           // s * p
            const float2 a = cur[b];
            const float2 c = cur[b + 512];
            const float sr = a.x + c.x, sim = a.y + c.y;
            const float dr = a.x - c.x, dim = a.y - c.y;
            float st, ct;
            __sincosf(PI_OVER_512 * (float)j, &st, &ct);
            nxt[b + j]     = make_float2(sr, sim);
            nxt[b + j + s] = make_float2(ct * dr - st * dim, ct * dim + st * dr);
        }
        __syncthreads();
        float2* tmp = cur; cur = nxt; nxt = tmp;
    }
    // 10 swaps -> result back in sA (== cur)

    // ---- stage D: x[2m]=Re, x[2m+1]=Im (scale already folded), coalesced ----
    float2* outv = (float2*)(out + (size_t)h * LL);
    #pragma unroll
    for (int rep = 0; rep < FPT; ++rep) {
        const int m = t + rep * NT;
        outv[m] = cur[m];
    }
}

extern "C" void kernel_launch(void* const* d_in, const int* in_sizes, int n_in,
                              void* d_out, int out_size, void* d_ws, size_t ws_size,
                              hipStream_t stream) {
    const float* C  = (const float*)d_in[0];
    const float* B  = (const float*)d_in[1];
    const float* P  = (const float*)d_in[2];
    const float* W  = (const float*)d_in[3];
    const float* ld = (const float*)d_in[4];
    // d_in[5] is L == 2048, compiled in as LL.
    float* out = (float*)d_out;
    ssk_fused<<<HH, NT, 0, stream>>>(C, B, P, W, ld, out);
}

// Round 4
// 75.008 us; speedup vs baseline: 1.1527x; 1.0030x over previous
//
#include <hip/hip_runtime.h>

// SSKernelNPLR: Cauchy + rank-1 Woodbury + irfft(L=2048), H=256, N=64.
// R4: radix-4 Stockham IFFT (5 stages, barriers 10->5), Hermitian pack folded
// into FFT stage 0 (saves a barrier + a full LDS pass), w^2/w^3 twiddles via
// double/triple-angle (1 sincos per butterfly, angles < pi/2), float4 stores.
// Stage A (Cauchy, VALU-bound, ~14 pk-slots/n/f) unchanged from R3.

typedef float v2f __attribute__((ext_vector_type(2)));

#define HH 256
#define NN 64
#define LL 2048
#define MM 1024   // LL/2
#define NT 256    // threads per block (4 waves)
#define FPT 4     // f values per thread in stage A

#define PI_OVER_1024 0.0030679615757712823f  // 2*pi/2048
#define PI_OVER_512  0.0061359231515425647f  // 2*pi/1024

__global__ __launch_bounds__(NT) void ssk_fused(
    const float* __restrict__ Cin, const float* __restrict__ Bin,
    const float* __restrict__ Pin, const float* __restrict__ Win,
    const float* __restrict__ logdt, float* __restrict__ out)
{
    // per-n staging: [n*3+0]={wd.x,wd.y,v00.x,v00.y} [n*3+1]={v01.x,v01.y,v10.x,v10.y}
    //                [n*3+2]={v11r, -, -, -}
    __shared__ float4 sD4[NN * 3];
    __shared__ float2 sX[MM + 1]; // k_f, f = 0..1024
    __shared__ float2 sA[MM];     // FFT ping
    __shared__ float2 sBf[MM];    // FFT pong

    const int h = blockIdx.x;
    const int t = threadIdx.x;
    const float dtv = __expf(logdt[h]);

    // ---- stage 0: per-n products into LDS + analytic f=1024 term ----
    if (t < NN) {   // t<64 == wave 0 exactly
        const int base = (h * NN + t) * 2;
        const float Br = Bin[base], Bi = Bin[base + 1];
        const float Cr = Cin[base], Ci = Cin[base + 1];
        const float Pr = Pin[base], Pi = Pin[base + 1];
        const float v00r = Br * Cr - Bi * Ci, v00i = Br * Ci + Bi * Cr;
        sD4[t * 3 + 0] = make_float4(Win[base] * dtv, Win[base + 1] * dtv, v00r, v00i);
        sD4[t * 3 + 1] = make_float4(Br * Pr + Bi * Pi, Bi * Pr - Br * Pi,
                                     Pr * Cr - Pi * Ci, Pr * Ci + Pi * Cr);
        sD4[t * 3 + 2] = make_float4(Pr * Pr + Pi * Pi, 0.f, 0.f, 0.f);
        // f = L/2: omega=-1 -> u=0, den=4, Woodbury term vanishes:
        // k_f[1024] = 2*dt*sum_n(v00)/4 = dt*sum(v00r)/2  (imag forced 0)
        float r = v00r;
        #pragma unroll
        for (int off = 32; off; off >>= 1) r += __shfl_xor(r, off, 64);
        if (t == 0) sX[MM] = make_float2(0.5f * dtv * r, 0.f);
    }
    __syncthreads();

    // ---- stage A: Cauchy + Woodbury -> sX[f], f = t + rep*256 ----
    // u = 1+omega; den_n = 2(1-omega) - w_dt[n]*u ; 1/(z-w_dt) = u/den
    // k_f = 2*dt*( s00 - dt*u*s01*s10 / (1 + dt*u*s11) )   [2/(1+omega) folded]
    {
        const float* sDf = (const float*)sD4;
        v2f u[FPT], t1[FPT];
        v2f s00[FPT], s01[FPT], s10[FPT], s11[FPT];
        #pragma unroll
        for (int rep = 0; rep < FPT; ++rep) {
            const int f = t + rep * NT;
            float si, co;
            __sincosf(PI_OVER_1024 * (float)f, &si, &co);
            u[rep]  = (v2f){1.0f + co, -si};
            t1[rep] = (v2f){2.0f * (1.0f - co), 2.0f * si};
            s00[rep] = (v2f){0.f, 0.f}; s01[rep] = (v2f){0.f, 0.f};
            s10[rep] = (v2f){0.f, 0.f}; s11[rep] = (v2f){0.f, 0.f};
        }
        #pragma unroll 4
        for (int n = 0; n < NN; ++n) {
            const float4 q0 = sD4[n * 3 + 0];   // wd.x wd.y v00r v00i
            const float4 q1 = sD4[n * 3 + 1];   // v01r v01i v10r v10i
            const float v11 = sDf[n * 12 + 8];
            #pragma unroll
            for (int rep = 0; rep < FPT; ++rep) {
                v2f den = t1[rep];
                den = den - (v2f){q0.x, q0.x} * u[rep];
                den = den + (v2f){q0.y, q0.y} * (v2f){u[rep].y, -u[rep].x};
                const float inv = __builtin_amdgcn_rcpf(den.x * den.x + den.y * den.y);
                const v2f e  = den * (v2f){inv, -inv};  // 1/den = conj(den)/|den|^2
                const v2f es = {e.y, e.x};
                s00[rep] = s00[rep] + (v2f){q0.z, q0.z} * e;
                s00[rep] = s00[rep] + (v2f){-q0.w, q0.w} * es;
                s01[rep] = s01[rep] + (v2f){q1.x, q1.x} * e;
                s01[rep] = s01[rep] + (v2f){-q1.y, q1.y} * es;
                s10[rep] = s10[rep] + (v2f){q1.z, q1.z} * e;
                s10[rep] = s10[rep] + (v2f){-q1.w, q1.w} * es;
                s11[rep] = s11[rep] + (v2f){v11, v11} * e;   // v11 imag == 0
            }
        }
        #pragma unroll
        for (int rep = 0; rep < FPT; ++rep) {
            const int f = t + rep * NT;
            const float gr = dtv * u[rep].x, gi = dtv * u[rep].y;      // g = dt*u
            const float numr = s01[rep].x * s10[rep].x - s01[rep].y * s10[rep].y;
            const float numi = s01[rep].x * s10[rep].y + s01[rep].y * s10[rep].x;
            const float qr = 1.0f + (gr * s11[rep].x - gi * s11[rep].y); // 1+g*s11
            const float qi = gr * s11[rep].y + gi * s11[rep].x;
            const float tr = gr * numr - gi * numi;                      // g*num
            const float ti = gr * numi + gi * numr;
            const float qinv = __builtin_amdgcn_rcpf(qr * qr + qi * qi);
            const float cr = (tr * qr + ti * qi) * qinv;
            const float ci = (ti * qr - tr * qi) * qinv;
            const float kr = 2.0f * dtv * (s00[rep].x - cr);
            float       ki = 2.0f * dtv * (s00[rep].y - ci);
            if (f == 0) ki = 0.0f;   // pocketfft c2r ignores Im at DC
            sX[f] = make_float2(kr, ki);
        }
    }
    __syncthreads();

    // ---- FFT stage 0 (radix-4, s=1) with Hermitian pack folded in ----
    // pack(f): E=(X[f]+conj(X[M-f]))/2 ; O=e^{+i*pi*f/M}*(X[f]-conj(X[M-f]))/2
    //          z = (E - Im O*i ...) == (er - Oi, eim + Or), scale 1/M folded.
    const float HS = 4.8828125e-4f;  // 0.5 / 1024
    float2* cur;
    float2* nxt;
    {
        const int b = t;
        float2 Z[4];
        #pragma unroll
        for (int r = 0; r < 4; ++r) {
            const int f = b + r * 256;
            const float2 a1 = sX[f];
            const float2 x2 = sX[MM - f];
            const float er  = HS * (a1.x + x2.x), eim = HS * (a1.y - x2.y);
            const float gr  = HS * (a1.x - x2.x), gim = HS * (a1.y + x2.y);
            float st, ct;
            __sincosf(PI_OVER_1024 * (float)f, &st, &ct);
            Z[r] = make_float2(er - (ct * gim + st * gr), eim + (ct * gr - st * gim));
        }
        // radix-4 butterfly, s=1, j=b, w = e^{+2*pi*i/1024}
        const float2 T0 = {Z[0].x + Z[2].x, Z[0].y + Z[2].y};
        const float2 T1 = {Z[1].x + Z[3].x, Z[1].y + Z[3].y};
        const float2 T2 = {Z[0].x - Z[2].x, Z[0].y - Z[2].y};
        const float2 D3 = {Z[1].x - Z[3].x, Z[1].y - Z[3].y};
        const float2 T3 = {-D3.y, D3.x};                 // +i*(Z1-Z3)
        float s1, c1;
        __sincosf(PI_OVER_512 * (float)b, &s1, &c1);
        const float c2 = 1.f - 2.f * s1 * s1, s2 = 2.f * s1 * c1;
        const float c3 = c1 * c2 - s1 * s2,  s3 = s1 * c2 + c1 * s2;
        const float2 A0 = {T0.x + T1.x, T0.y + T1.y};
        const float2 A1 = {T2.x + T3.x, T2.y + T3.y};
        const float2 A2 = {T0.x - T1.x, T0.y - T1.y};
        const float2 A3 = {T2.x - T3.x, T2.y - T3.y};
        sBf[4 * b + 0] = A0;
        sBf[4 * b + 1] = make_float2(c1 * A1.x - s1 * A1.y, c1 * A1.y + s1 * A1.x);
        sBf[4 * b + 2] = make_float2(c2 * A2.x - s2 * A2.y, c2 * A2.y + s2 * A2.x);
        sBf[4 * b + 3] = make_float2(c3 * A3.x - s3 * A3.y, c3 * A3.y + s3 * A3.x);
        cur = sBf; nxt = sA;
        __syncthreads();
    }

    // ---- FFT stages 1..4 (radix-4 Stockham, s = 4,16,64,256) ----
    #pragma unroll
    for (int i = 1; i < 5; ++i) {
        const int s = 1 << (2 * i);
        const int b = t;
        const int j = b & ~(s - 1);              // p*s  (j < 256 -> angle < pi/2)
        const float2 X0 = cur[b], X1 = cur[b + 256], X2 = cur[b + 512], X3 = cur[b + 768];
        const float2 T0 = {X0.x + X2.x, X0.y + X2.y};
        const float2 T1 = {X1.x + X3.x, X1.y + X3.y};
        const float2 T2 = {X0.x - X2.x, X0.y - X2.y};
        const float2 D3 = {X1.x - X3.x, X1.y - X3.y};
        const float2 T3 = {-D3.y, D3.x};         // +i*(X1-X3)
        float s1, c1;
        __sincosf(PI_OVER_512 * (float)j, &s1, &c1);
        const float c2 = 1.f - 2.f * s1 * s1, s2 = 2.f * s1 * c1;
        const float c3 = c1 * c2 - s1 * s2,  s3 = s1 * c2 + c1 * s2;
        const int o = b + 3 * j;                 // q + 4*p*s
        const float2 A0 = {T0.x + T1.x, T0.y + T1.y};
        const float2 A1 = {T2.x + T3.x, T2.y + T3.y};
        const float2 A2 = {T0.x - T1.x, T0.y - T1.y};
        const float2 A3 = {T2.x - T3.x, T2.y - T3.y};
        nxt[o]         = A0;
        nxt[o + s]     = make_float2(c1 * A1.x - s1 * A1.y, c1 * A1.y + s1 * A1.x);
        nxt[o + 2 * s] = make_float2(c2 * A2.x - s2 * A2.y, c2 * A2.y + s2 * A2.x);
        nxt[o + 3 * s] = make_float2(c3 * A3.x - s3 * A3.y, c3 * A3.y + s3 * A3.x);
        __syncthreads();
        float2* tmp = cur; cur = nxt; nxt = tmp;
    }
    // 5 total stages, result in cur (== sBf)

    // ---- stage D: x[2m]=Re, x[2m+1]=Im (scale folded), float4 stores ----
    float4* outv4 = (float4*)(out + (size_t)h * LL);
    #pragma unroll
    for (int rep = 0; rep < 2; ++rep) {
        const int m = t + rep * NT;              // m in [0,512): two complex -> float4
        const float2 z0 = cur[2 * m], z1 = cur[2 * m + 1];
        outv4[m] = make_float4(z0.x, z0.y, z1.x, z1.y);
    }
}

extern "C" void kernel_launch(void* const* d_in, const int* in_sizes, int n_in,
                              void* d_out, int out_size, void* d_ws, size_t ws_size,
                              hipStream_t stream) {
    const float* C  = (const float*)d_in[0];
    const float* B  = (const float*)d_in[1];
    const float* P  = (const float*)d_in[2];
    const float* W  = (const float*)d_in[3];
    const float* ld = (const float*)d_in[4];
    // d_in[5] is L == 2048, compiled in as LL.
    float* out = (float*)d_out;
    ssk_fused<<<HH, NT, 0, stream>>>(C, B, P, W, ld, out);
}